// Round 1
// baseline (153.890 us; speedup 1.0000x reference)
//
#include <hip/hip_runtime.h>
#include <float.h>
#include <math.h>

// Problem constants (fixed by reference)
#define NB    8
#define K1    2048
#define K2    8192
#define NADD  16
#define PP    128          // K1 / NADD
#define FEPS  1e-7f
#define CDW   0.1f

// chamfer tiling
#define OCH   8            // ori chunks
#define OCLEN (K2 / OCH)   // 1024

// ws layout (float offsets)
#define OPACK_OFF 0
#define PMIN_OFF  (NB * K2 * 4)               // 262144
#define FAR_OFF   (PMIN_OFF + NB * K1 * OCH)  // 393216
#define CHB_OFF   (FAR_OFF + NB * NADD)       // 393344
// total floats = 393352  (~1.54 MB) -- well under typical ws_size

// ---------------------------------------------------------------------------
// Kernel 1: pack ori points as [x, y, z, x^2+y^2+z^2]
// ---------------------------------------------------------------------------
__global__ __launch_bounds__(256) void prep_ori(const float* __restrict__ ori,
                                                float4* __restrict__ opack) {
    int i = blockIdx.x * 256 + threadIdx.x;   // 0 .. NB*K2-1
    if (i < NB * K2) {
        float x = ori[i * 3 + 0];
        float y = ori[i * 3 + 1];
        float z = ori[i * 3 + 2];
        opack[i] = make_float4(x, y, z, fmaf(x, x, fmaf(y, y, z * z)));
    }
}

// ---------------------------------------------------------------------------
// Kernel 2: farthest pairwise distance per (batch, cluster)
// delta[p][q] = c[q] - c[p] + EPS (per coord); far = sqrt(max over p,q of |delta|^2)
// ---------------------------------------------------------------------------
__global__ __launch_bounds__(128) void farthest_k(const float* __restrict__ adv,
                                                  float* __restrict__ far) {
    const int ci = blockIdx.x;   // cluster 0..15
    const int b  = blockIdx.y;   // batch 0..7
    const int p  = threadIdx.x;  // 0..127

    __shared__ float sx[PP], sy[PP], sz[PP];
    const float* c = adv + (size_t)(b * K1 + ci * PP) * 3;
    float px = c[p * 3 + 0];
    float py = c[p * 3 + 1];
    float pz = c[p * 3 + 2];
    sx[p] = px; sy[p] = py; sz[p] = pz;
    __syncthreads();

    // dx = c_q - c_p + EPS = sx[q] - (px - EPS)
    const float pxm = px - FEPS, pym = py - FEPS, pzm = pz - FEPS;
    float mx = 0.f;
#pragma unroll 8
    for (int q = 0; q < PP; ++q) {
        float dx = sx[q] - pxm;
        float dy = sy[q] - pym;
        float dz = sz[q] - pzm;
        mx = fmaxf(mx, fmaf(dx, dx, fmaf(dy, dy, dz * dz)));
    }

    // reduce max over 128 threads (2 waves)
#pragma unroll
    for (int off = 32; off; off >>= 1) mx = fmaxf(mx, __shfl_down(mx, off, 64));
    __shared__ float sred[2];
    if ((p & 63) == 0) sred[p >> 6] = mx;
    __syncthreads();
    if (p == 0) far[b * NADD + ci] = sqrtf(fmaxf(sred[0], sred[1]));
}

// ---------------------------------------------------------------------------
// Kernel 3: chamfer partial mins.  grid (OCH, K1/256, NB), 256 thr.
// Per thread: one adv point, scan OCLEN ori points of one chunk.
// Stores min over chunk of (o^2 - 2 a.o); a^2 and clamp folded in later
// (both commute with min).
// ---------------------------------------------------------------------------
__global__ __launch_bounds__(256) void chamfer_partial(const float* __restrict__ adv,
                                                       const float4* __restrict__ opack,
                                                       float* __restrict__ pmins) {
    const int oc = blockIdx.x;            // ori chunk 0..7
    const int kc = blockIdx.y;            // adv chunk 0..7
    const int b  = blockIdx.z;            // batch
    const int k  = kc * 256 + threadIdx.x;

    const float* a = adv + (size_t)(b * K1 + k) * 3;
    const float ax = a[0], ay = a[1], az = a[2];
    const float bx = -2.f * ax, by = -2.f * ay, bz = -2.f * az;

    const float4* op = opack + (size_t)b * K2 + oc * OCLEN;  // wave-uniform base
    float dmin = FLT_MAX;
#pragma unroll 8
    for (int m = 0; m < OCLEN; ++m) {
        float4 o = op[m];                 // uniform index -> scalar loads
        // t = o^2 - 2 a.o   (keep <=1 sgpr operand per VALU op)
        float t = fmaf(bx, o.x, fmaf(by, o.y, bz * o.z));
        dmin = fminf(dmin, t + o.w);
    }
    pmins[(size_t)(b * K1 + k) * OCH + oc] = dmin;
}

// ---------------------------------------------------------------------------
// Kernel 4: per-batch chamfer reduce: min over chunks, +a^2, clamp, mean
// ---------------------------------------------------------------------------
__global__ __launch_bounds__(256) void chamfer_reduce(const float* __restrict__ adv,
                                                      const float* __restrict__ pmins,
                                                      float* __restrict__ chb) {
    const int b = blockIdx.x;
    float sum = 0.f;
    for (int k = threadIdx.x; k < K1; k += 256) {
        const float* pm = pmins + (size_t)(b * K1 + k) * OCH;   // 32B aligned
        float4 m0 = *reinterpret_cast<const float4*>(pm);
        float4 m1 = *reinterpret_cast<const float4*>(pm + 4);
        float m = fminf(fminf(fminf(m0.x, m0.y), fminf(m0.z, m0.w)),
                        fminf(fminf(m1.x, m1.y), fminf(m1.z, m1.w)));
        const float* a = adv + (size_t)(b * K1 + k) * 3;
        float ax = a[0], ay = a[1], az = a[2];
        float a2 = fmaf(ax, ax, fmaf(ay, ay, az * az));
        sum += fmaxf(a2 + m, 0.f);
    }
    // block reduce sum over 4 waves
#pragma unroll
    for (int off = 32; off; off >>= 1) sum += __shfl_down(sum, off, 64);
    __shared__ float s[4];
    int lane = threadIdx.x & 63, wid = threadIdx.x >> 6;
    if (lane == 0) s[wid] = sum;
    __syncthreads();
    if (threadIdx.x == 0) chb[b] = (s[0] + s[1] + s[2] + s[3]) * (1.f / K1);
}

// ---------------------------------------------------------------------------
// Kernel 5: final scalar combine
// out = (1/8) sum_b w_b * sum_ci far[b,ci]  +  (0.1/8) sum_b w_b * chb[b]
// ---------------------------------------------------------------------------
__global__ __launch_bounds__(128) void final_combine(const float* __restrict__ far,
                                                     const float* __restrict__ chb,
                                                     const float* __restrict__ w,
                                                     float* __restrict__ out) {
    int t = threadIdx.x;  // 0..127
    float v = w[t >> 4] * far[t] * 0.125f;
    if (t < NB) v += (CDW * 0.125f) * w[t] * chb[t];
#pragma unroll
    for (int off = 32; off; off >>= 1) v += __shfl_down(v, off, 64);
    __shared__ float s[2];
    if ((t & 63) == 0) s[t >> 6] = v;
    __syncthreads();
    if (t == 0) out[0] = s[0] + s[1];
}

// ---------------------------------------------------------------------------
extern "C" void kernel_launch(void* const* d_in, const int* in_sizes, int n_in,
                              void* d_out, int out_size, void* d_ws, size_t ws_size,
                              hipStream_t stream) {
    const float* adv = (const float*)d_in[0];
    const float* ori = (const float*)d_in[1];
    const float* w   = (const float*)d_in[2];
    float* ws    = (float*)d_ws;
    float4* opack = (float4*)(ws + OPACK_OFF);
    float* pmins = ws + PMIN_OFF;
    float* far   = ws + FAR_OFF;
    float* chb   = ws + CHB_OFF;
    float* out   = (float*)d_out;

    prep_ori<<<dim3((NB * K2) / 256), 256, 0, stream>>>(ori, opack);
    farthest_k<<<dim3(NADD, NB), 128, 0, stream>>>(adv, far);
    chamfer_partial<<<dim3(OCH, K1 / 256, NB), 256, 0, stream>>>(adv, opack, pmins);
    chamfer_reduce<<<dim3(NB), 256, 0, stream>>>(adv, pmins, chb);
    final_combine<<<1, 128, 0, stream>>>(far, chb, w, out);
}

// Round 2
// 50.982 us; speedup vs baseline: 3.0185x; 3.0185x over previous
//
#include <hip/hip_runtime.h>
#include <float.h>
#include <math.h>

// Problem constants (fixed by reference)
#define NB    8
#define K1    2048
#define K2    8192
#define NADD  16
#define PP    128          // K1 / NUM_ADD
#define FEPS  1e-7f
#define CDW   0.1f

// chamfer tiling
#define OCH   64           // ori chunks (grid = OCH*NB = 512 blocks = 2/CU)
#define OCLEN (K2 / OCH)   // 128 ori points per chunk
#define MPT   8            // adv points per thread (independent min chains)

// ws layout (float offsets)
#define OPACK_OFF 0
#define PMIN_OFF  (NB * K2 * 4)                   // 262144
#define FAR_OFF   (PMIN_OFF + OCH * NB * K1)      // 262144 + 1048576
#define CHBP_OFF  (FAR_OFF + NB * NADD)
// total ~5.25 MB of ws

// ---------------------------------------------------------------------------
// Kernel 1: pack ori points as [x, y, z, x^2+y^2+z^2]
// ---------------------------------------------------------------------------
__global__ __launch_bounds__(256) void prep_ori(const float* __restrict__ ori,
                                                float4* __restrict__ opack) {
    int i = blockIdx.x * 256 + threadIdx.x;   // 0 .. NB*K2-1
    if (i < NB * K2) {
        float x = ori[i * 3 + 0];
        float y = ori[i * 3 + 1];
        float z = ori[i * 3 + 2];
        opack[i] = make_float4(x, y, z, fmaf(x, x, fmaf(y, y, z * z)));
    }
}

// ---------------------------------------------------------------------------
// Kernel 2: farthest pairwise distance per (batch, cluster)
// ---------------------------------------------------------------------------
__global__ __launch_bounds__(128) void farthest_k(const float* __restrict__ adv,
                                                  float* __restrict__ far) {
    const int ci = blockIdx.x;   // cluster 0..15
    const int b  = blockIdx.y;   // batch 0..7
    const int p  = threadIdx.x;  // 0..127

    __shared__ float sx[PP], sy[PP], sz[PP];
    const float* c = adv + (size_t)(b * K1 + ci * PP) * 3;
    float px = c[p * 3 + 0];
    float py = c[p * 3 + 1];
    float pz = c[p * 3 + 2];
    sx[p] = px; sy[p] = py; sz[p] = pz;
    __syncthreads();

    const float pxm = px - FEPS, pym = py - FEPS, pzm = pz - FEPS;
    float mx = 0.f;
#pragma unroll 8
    for (int q = 0; q < PP; ++q) {
        float dx = sx[q] - pxm;
        float dy = sy[q] - pym;
        float dz = sz[q] - pzm;
        mx = fmaxf(mx, fmaf(dx, dx, fmaf(dy, dy, dz * dz)));
    }
#pragma unroll
    for (int off = 32; off; off >>= 1) mx = fmaxf(mx, __shfl_down(mx, off, 64));
    __shared__ float sred[2];
    if ((p & 63) == 0) sred[p >> 6] = mx;
    __syncthreads();
    if (p == 0) far[b * NADD + ci] = sqrtf(fmaxf(sred[0], sred[1]));
}

// ---------------------------------------------------------------------------
// Kernel 3: chamfer partial mins.  grid (OCH, NB), 256 thr.
// Each thread owns MPT=8 adv points (8 independent min chains) and scans
// OCLEN ori points of its chunk. 4 VALU ops per (adv,ori) pair:
//   dmin = min(dmin, fma(bx,ox, fma(by,oy, fma(bz,oz, o2))))
// ---------------------------------------------------------------------------
__global__ __launch_bounds__(256) void chamfer_partial(const float* __restrict__ adv,
                                                       const float4* __restrict__ opack,
                                                       float* __restrict__ pmins) {
    const int oc = blockIdx.x;            // ori chunk 0..OCH-1
    const int b  = blockIdx.y;            // batch
    const int t  = threadIdx.x;

    float bx[MPT], by[MPT], bz[MPT], dmin[MPT];
#pragma unroll
    for (int j = 0; j < MPT; ++j) {
        const float* a = adv + (size_t)(b * K1 + t + 256 * j) * 3;
        bx[j] = -2.f * a[0];
        by[j] = -2.f * a[1];
        bz[j] = -2.f * a[2];
        dmin[j] = FLT_MAX;
    }

    const float4* op = opack + (size_t)b * K2 + oc * OCLEN;  // wave-uniform base
#pragma unroll 4
    for (int m = 0; m < OCLEN; ++m) {
        float4 o = op[m];                 // uniform address -> broadcast/scalar
#pragma unroll
        for (int j = 0; j < MPT; ++j) {
            dmin[j] = fminf(dmin[j],
                            fmaf(bx[j], o.x, fmaf(by[j], o.y, fmaf(bz[j], o.z, o.w))));
        }
    }

#pragma unroll
    for (int j = 0; j < MPT; ++j)         // coalesced: consecutive t -> consecutive addr
        pmins[((size_t)oc * NB + b) * K1 + t + 256 * j] = dmin[j];
}

// ---------------------------------------------------------------------------
// Kernel 4: min over chunks, +a^2, clamp, partial sum per (b, kc)
// grid (K1/256, NB), 256 thr, one thread per adv point.
// ---------------------------------------------------------------------------
__global__ __launch_bounds__(256) void chamfer_reduce(const float* __restrict__ adv,
                                                      const float* __restrict__ pmins,
                                                      float* __restrict__ chbp) {
    const int kc = blockIdx.x;            // 0..7
    const int b  = blockIdx.y;
    const int k  = kc * 256 + threadIdx.x;

    float m = FLT_MAX;
#pragma unroll 8
    for (int oc = 0; oc < OCH; ++oc)      // coalesced across threads each iter
        m = fminf(m, pmins[((size_t)oc * NB + b) * K1 + k]);

    const float* a = adv + (size_t)(b * K1 + k) * 3;
    float ax = a[0], ay = a[1], az = a[2];
    float a2 = fmaf(ax, ax, fmaf(ay, ay, az * az));
    float sum = fmaxf(a2 + m, 0.f);

#pragma unroll
    for (int off = 32; off; off >>= 1) sum += __shfl_down(sum, off, 64);
    __shared__ float s[4];
    int lane = threadIdx.x & 63, wid = threadIdx.x >> 6;
    if (lane == 0) s[wid] = sum;
    __syncthreads();
    if (threadIdx.x == 0) chbp[b * 8 + kc] = s[0] + s[1] + s[2] + s[3];
}

// ---------------------------------------------------------------------------
// Kernel 5: final scalar combine
// out = (1/8) sum_b w_b sum_ci far[b,ci] + (0.1/8/K1) sum_b w_b sum_kc chbp[b,kc]
// ---------------------------------------------------------------------------
__global__ __launch_bounds__(128) void final_combine(const float* __restrict__ far,
                                                     const float* __restrict__ chbp,
                                                     const float* __restrict__ w,
                                                     float* __restrict__ out) {
    int t = threadIdx.x;  // 0..127
    float v = w[t >> 4] * far[t] * 0.125f;
    if (t < 64) v += (CDW * 0.125f / K1) * w[t >> 3] * chbp[t];
#pragma unroll
    for (int off = 32; off; off >>= 1) v += __shfl_down(v, off, 64);
    __shared__ float s[2];
    if ((t & 63) == 0) s[t >> 6] = v;
    __syncthreads();
    if (t == 0) out[0] = s[0] + s[1];
}

// ---------------------------------------------------------------------------
extern "C" void kernel_launch(void* const* d_in, const int* in_sizes, int n_in,
                              void* d_out, int out_size, void* d_ws, size_t ws_size,
                              hipStream_t stream) {
    const float* adv = (const float*)d_in[0];
    const float* ori = (const float*)d_in[1];
    const float* w   = (const float*)d_in[2];
    float* ws     = (float*)d_ws;
    float4* opack = (float4*)(ws + OPACK_OFF);
    float* pmins  = ws + PMIN_OFF;
    float* far    = ws + FAR_OFF;
    float* chbp   = ws + CHBP_OFF;
    float* out    = (float*)d_out;

    prep_ori<<<dim3((NB * K2) / 256), 256, 0, stream>>>(ori, opack);
    farthest_k<<<dim3(NADD, NB), 128, 0, stream>>>(adv, far);
    chamfer_partial<<<dim3(OCH, NB), 256, 0, stream>>>(adv, opack, pmins);
    chamfer_reduce<<<dim3(K1 / 256, NB), 256, 0, stream>>>(adv, pmins, chbp);
    final_combine<<<1, 128, 0, stream>>>(far, chbp, w, out);
}

// Round 3
// 38.730 us; speedup vs baseline: 3.9734x; 1.3163x over previous
//
#include <hip/hip_runtime.h>
#include <float.h>
#include <math.h>

// Problem constants (fixed by reference)
#define NB    8
#define K1    2048
#define K2    8192
#define NADD  16
#define PP    128          // K1 / NUM_ADD
#define FEPS  1e-7f
#define CDW   0.1f

// chamfer tiling
#define OCH   64           // ori chunks
#define OCLEN (K2 / OCH)   // 128 ori points per chunk
#define KC    2            // adv halves
#define MPT   4            // adv points per thread (K1 / KC / 256)
#define CH_GRID  (OCH * KC * NB)   // 1024 chamfer blocks
#define FAR_GRID 64                // (b, cluster-pair) blocks
#define GRID_A   (CH_GRID + FAR_GRID)

// ws layout (float offsets)
#define PMIN_OFF 0
#define PMIN_SZ  (OCH * NB * K1)          // 1,048,576 floats (4 MB)
#define FARW_OFF PMIN_SZ
#define CHB_OFF  (FARW_OFF + NB * NADD)
#define CTR_OFF  (CHB_OFF + 64)

// ---------------------------------------------------------------------------
// Kernel A: fused chamfer-partial (blocks 0..1023) + farthest (blocks 1024..1087)
// ---------------------------------------------------------------------------
__global__ __launch_bounds__(256) void fused_a(const float* __restrict__ adv,
                                               const float* __restrict__ ori,
                                               float* __restrict__ pmins,
                                               float* __restrict__ far,
                                               unsigned int* __restrict__ ctr) {
    __shared__ float4 s4[192];        // chamfer: 128 float4; farthest: 768 floats
    __shared__ float sred[4];
    const int bid = blockIdx.x;
    const int t   = threadIdx.x;
    if (bid == 0 && t == 0) *ctr = 0u;   // reset kernel-B completion counter

    if (bid < CH_GRID) {
        // ---- chamfer partial: chunk oc of batch b vs adv half kc ----
        const int oc = bid & (OCH - 1);
        const int kc = (bid >> 6) & (KC - 1);
        const int b  = bid >> 7;

        if (t < OCLEN) {               // stage + pack this chunk's ori points
            const float* o = ori + ((size_t)b * K2 + oc * OCLEN + t) * 3;
            float x = o[0], y = o[1], z = o[2];
            s4[t] = make_float4(x, y, z, fmaf(x, x, fmaf(y, y, z * z)));
        }
        __syncthreads();

        float bx[MPT], by[MPT], bz[MPT], dmin[MPT];
        const int k0 = kc * (K1 / KC) + t;
#pragma unroll
        for (int j = 0; j < MPT; ++j) {
            const float* a = adv + (size_t)(b * K1 + k0 + 256 * j) * 3;
            bx[j] = -2.f * a[0];
            by[j] = -2.f * a[1];
            bz[j] = -2.f * a[2];
            dmin[j] = FLT_MAX;
        }

#pragma unroll 8
        for (int m = 0; m < OCLEN; ++m) {
            float4 o = s4[m];          // uniform address -> LDS broadcast, no conflict
#pragma unroll
            for (int j = 0; j < MPT; ++j)
                dmin[j] = fminf(dmin[j],
                                fmaf(bx[j], o.x, fmaf(by[j], o.y, fmaf(bz[j], o.z, o.w))));
        }

#pragma unroll
        for (int j = 0; j < MPT; ++j)  // coalesced
            pmins[((size_t)oc * NB + b) * K1 + k0 + 256 * j] = dmin[j];
    } else {
        // ---- farthest: block handles (b, cluster-pair), 128 threads/cluster ----
        const int fb = bid - CH_GRID;
        const int b  = fb >> 3;
        const int cp = fb & 7;
        const int g  = t >> 7;        // 0/1: which cluster of the pair
        const int p  = t & 127;
        const int ci = cp * 2 + g;

        float* sf = (float*)s4;       // [2][3][128]
        const float* c = adv + (size_t)(b * K1 + ci * PP) * 3;
        float px = c[p * 3 + 0], py = c[p * 3 + 1], pz = c[p * 3 + 2];
        float* sx = sf + g * 384;
        sx[p] = px; sx[128 + p] = py; sx[256 + p] = pz;
        __syncthreads();

        const float pxm = px - FEPS, pym = py - FEPS, pzm = pz - FEPS;
        float mx = 0.f;
#pragma unroll 8
        for (int q = 0; q < PP; ++q) {
            float dx = sx[q] - pxm;
            float dy = sx[128 + q] - pym;
            float dz = sx[256 + q] - pzm;
            mx = fmaxf(mx, fmaf(dx, dx, fmaf(dy, dy, dz * dz)));
        }
#pragma unroll
        for (int off = 32; off; off >>= 1) mx = fmaxf(mx, __shfl_down(mx, off, 64));
        if ((t & 63) == 0) sred[t >> 6] = mx;
        __syncthreads();
        if (t == 0)   far[b * NADD + cp * 2 + 0] = sqrtf(fmaxf(sred[0], sred[1]));
        if (t == 128) far[b * NADD + cp * 2 + 1] = sqrtf(fmaxf(sred[2], sred[3]));
    }
}

// ---------------------------------------------------------------------------
// Kernel B: min over chunks + clamp + per-(b,kc) sum; last-done block combines.
// grid 64 blocks x 256 thr; block (kc,b) handles adv points kc*256..kc*256+255.
// ---------------------------------------------------------------------------
__global__ __launch_bounds__(256) void reduce_b(const float* __restrict__ adv,
                                                const float* __restrict__ pmins,
                                                const float* __restrict__ far,
                                                const float* __restrict__ w,
                                                float* __restrict__ chbp,
                                                unsigned int* __restrict__ ctr,
                                                float* __restrict__ out) {
    __shared__ float s[4];
    __shared__ unsigned int lastflag;
    const int t  = threadIdx.x;
    const int kc = blockIdx.x & 7;
    const int b  = blockIdx.x >> 3;
    const int k  = kc * 256 + t;

    float m = FLT_MAX;
#pragma unroll 8
    for (int oc = 0; oc < OCH; ++oc)   // coalesced across threads each iter
        m = fminf(m, pmins[((size_t)oc * NB + b) * K1 + k]);

    const float* a = adv + (size_t)(b * K1 + k) * 3;
    float ax = a[0], ay = a[1], az = a[2];
    float a2 = fmaf(ax, ax, fmaf(ay, ay, az * az));
    float sum = fmaxf(a2 + m, 0.f);

#pragma unroll
    for (int off = 32; off; off >>= 1) sum += __shfl_down(sum, off, 64);
    const int lane = t & 63, wid = t >> 6;
    if (lane == 0) s[wid] = sum;
    __syncthreads();

    if (t == 0) {
        float part = s[0] + s[1] + s[2] + s[3];
        __hip_atomic_store(&chbp[b * 8 + kc], part,
                           __ATOMIC_RELEASE, __HIP_MEMORY_SCOPE_AGENT);
        unsigned int old = __hip_atomic_fetch_add(ctr, 1u,
                           __ATOMIC_ACQ_REL, __HIP_MEMORY_SCOPE_AGENT);
        lastflag = (old == 63u) ? 1u : 0u;
    }
    __syncthreads();
    if (!lastflag) return;

    // ---- final combine (single block, fixed order -> deterministic) ----
    float v = 0.f;
    if (t < 128) v = w[t >> 4] * far[t] * 0.125f;
    if (t < 64)
        v += (CDW * 0.125f / K1) * w[t >> 3] *
             __hip_atomic_load(&chbp[t], __ATOMIC_ACQUIRE, __HIP_MEMORY_SCOPE_AGENT);
#pragma unroll
    for (int off = 32; off; off >>= 1) v += __shfl_down(v, off, 64);
    __syncthreads();                 // protect s[] reuse
    if (lane == 0) s[wid] = v;
    __syncthreads();
    if (t == 0) out[0] = s[0] + s[1] + s[2] + s[3];
}

// ---------------------------------------------------------------------------
extern "C" void kernel_launch(void* const* d_in, const int* in_sizes, int n_in,
                              void* d_out, int out_size, void* d_ws, size_t ws_size,
                              hipStream_t stream) {
    const float* adv = (const float*)d_in[0];
    const float* ori = (const float*)d_in[1];
    const float* w   = (const float*)d_in[2];
    float* ws    = (float*)d_ws;
    float* pmins = ws + PMIN_OFF;
    float* far   = ws + FARW_OFF;
    float* chbp  = ws + CHB_OFF;
    unsigned int* ctr = (unsigned int*)(ws + CTR_OFF);
    float* out   = (float*)d_out;

    fused_a<<<dim3(GRID_A), 256, 0, stream>>>(adv, ori, pmins, far, ctr);
    reduce_b<<<dim3(64), 256, 0, stream>>>(adv, pmins, far, w, chbp, ctr, out);
}